// Round 1
// baseline (259.770 us; speedup 1.0000x reference)
//
#include <hip/hip_runtime.h>
#include <math.h>

#define BB 32
#define QQ 300
#define CC 91
#define TOPK 50
#define NKEEP 256
#define ML 128
#define QC (QQ * CC)        // 27300
#define NCH 8
#define CHUNK 3413          // ceil(27300/8)
#define PERT 14             // ceil(3413/256)

// output layout (flat float32, reference return order)
#define OFF_SCORES ((size_t)0)
#define OFF_LABELS ((size_t)1600)
#define OFF_BOXES  ((size_t)3200)
#define OFF_MASKS  ((size_t)9600)
#define OFF_SI     ((size_t)26224000)
#define OFF_LI     ((size_t)26225600)
#define OFF_LA     ((size_t)26227200)

// ---------------- init: DCT rows 0..22 (fp64 -> fp32) + zigzag table ----------------
__global__ void init_tables(float* __restrict__ wsD, int* __restrict__ wsZZ) {
    int idx = blockIdx.x * 256 + threadIdx.x;
    if (idx < 23 * 128) {
        int k = idx >> 7, m = idx & 127;
        // matches numpy: cos(pi*(2m+1)*k/(2n)) * sqrt(2/n), row0 *= sqrt(0.5), all in f64
        double v = cos((M_PI * (2.0 * (double)m + 1.0) * (double)k) / 256.0) * 0.125;
        if (k == 0) v *= sqrt(0.5);
        wsD[idx] = (float)v;
    }
    if (idx == 0) {
        // first 256 positions of the 128x128 zigzag order; pack (r<<5)|c  (r,c <= 22)
        int j = 0;
        for (int s = 0; j < NKEEP; ++s) {
            if ((s & 1) == 0) {
                int rhi = (s < 127) ? s : 127;
                int rlo = (s > 127) ? (s - 127) : 0;
                for (int r = rhi; r >= rlo && j < NKEEP; --r) wsZZ[j++] = (r << 5) | (s - r);
            } else {
                int rlo = (s > 127) ? (s - 127) : 0;
                int rhi = (s < 127) ? s : 127;
                for (int r = rlo; r <= rhi && j < NKEEP; ++r) wsZZ[j++] = (r << 5) | (s - r);
            }
        }
    }
}

// ---------------- phase A: per-(batch,chunk) top-50 via iterative argmax ----------------
__global__ __launch_bounds__(256) void topk_partial(const float* __restrict__ logits,
                                                    float* __restrict__ cv, int* __restrict__ cp) {
    int b = blockIdx.x >> 3, ch = blockIdx.x & 7;
    int t = threadIdx.x;
    int cstart = ch * CHUNK;
    int count = QC - cstart; if (count > CHUNK) count = CHUNK;
    const float* base = logits + (size_t)b * QC + cstart;

    float v[PERT];
#pragma unroll
    for (int i = 0; i < PERT; ++i) {
        int p = t + 256 * i;
        v[i] = (p < count) ? base[p] : -INFINITY;
    }

    __shared__ float sv[4];
    __shared__ int   si[4];
    int lane = t & 63, w = t >> 6;

    for (int it = 0; it < TOPK; ++it) {
        float bv = -INFINITY; int bi = 0x7fffffff;
#pragma unroll
        for (int i = 0; i < PERT; ++i) {
            int p = cstart + t + 256 * i;
            bool better = (v[i] > bv) || (v[i] == bv && p < bi);
            bv = better ? v[i] : bv;
            bi = better ? p : bi;
        }
#pragma unroll
        for (int off = 32; off >= 1; off >>= 1) {
            float ov = __shfl_down(bv, off);
            int   oi = __shfl_down(bi, off);
            bool better = (ov > bv) || (ov == bv && oi < bi);
            bv = better ? ov : bv;
            bi = better ? oi : bi;
        }
        __syncthreads();               // guard LDS reuse from previous iteration
        if (lane == 0) { sv[w] = bv; si[w] = bi; }
        __syncthreads();
        float gv = sv[0]; int gi = si[0];
#pragma unroll
        for (int k = 1; k < 4; ++k) {
            float ov = sv[k]; int oi = si[k];
            bool better = (ov > gv) || (ov == gv && oi < gi);
            gv = better ? ov : gv;
            gi = better ? oi : gi;
        }
        if (t == 0) {
            int o = (b * NCH + ch) * TOPK + it;
            cv[o] = gv; cp[o] = gi;
        }
#pragma unroll
        for (int i = 0; i < PERT; ++i) {
            int p = cstart + t + 256 * i;
            if (p == gi) v[i] = -INFINITY;
        }
    }
}

// ---------------- phase B: merge 400 candidates/batch + small outputs ----------------
__global__ __launch_bounds__(64) void topk_merge(const float* __restrict__ cv, const int* __restrict__ cp,
                                                 const float* __restrict__ bbox,
                                                 const float* __restrict__ actions,
                                                 const int* __restrict__ tsz,
                                                 float* __restrict__ out, int* __restrict__ wsQ) {
    int b = blockIdx.x;
    int lane = threadIdx.x;
    const int NC = NCH * TOPK;   // 400

    float v[7]; int p[7];
#pragma unroll
    for (int i = 0; i < 7; ++i) {
        int idx = lane + 64 * i;
        if (idx < NC) { v[i] = cv[b * NC + idx]; p[i] = cp[b * NC + idx]; }
        else          { v[i] = -INFINITY;        p[i] = 0x7fffffff; }
    }

    float selv = 0.0f; int selp = 0;
    for (int it = 0; it < TOPK; ++it) {
        float bv = -INFINITY; int bi = 0x7fffffff;
#pragma unroll
        for (int i = 0; i < 7; ++i) {
            bool better = (v[i] > bv) || (v[i] == bv && p[i] < bi);
            bv = better ? v[i] : bv;
            bi = better ? p[i] : bi;
        }
#pragma unroll
        for (int off = 32; off >= 1; off >>= 1) {
            float ov = __shfl_down(bv, off);
            int   oi = __shfl_down(bi, off);
            bool better = (ov > bv) || (ov == bv && oi < bi);
            bv = better ? ov : bv;
            bi = better ? oi : bi;
        }
        bv = __shfl(bv, 0); bi = __shfl(bi, 0);
        if (it == lane) { selv = bv; selp = bi; }
#pragma unroll
        for (int i = 0; i < 7; ++i) if (p[i] == bi) v[i] = -INFINITY;
    }

    if (lane < TOPK) {
        int q = selp / CC;
        int label = selp - q * CC;
        out[OFF_SCORES + b * TOPK + lane] = 1.0f / (1.0f + expf(-selv));
        out[OFF_LABELS + b * TOPK + lane] = (float)label;
        wsQ[b * TOPK + lane] = q;
        const float* bbp = bbox + ((size_t)(b * QQ + q)) * 4;
        float cx = bbp[0], cy = bbp[1], bw = bbp[2], bh = bbp[3];
        float ih = (float)tsz[b * 2 + 0];
        float iw = (float)tsz[b * 2 + 1];
        float* bo = out + OFF_BOXES + ((size_t)(b * TOPK + lane)) * 4;
        bo[0] = (cx - 0.5f * bw) * iw;
        bo[1] = (cy - 0.5f * bh) * ih;
        bo[2] = (cx + 0.5f * bw) * iw;
        bo[3] = (cy + 0.5f * bh) * ih;
    }
    if (lane == 0) {
        const float* ap = actions + (size_t)b * 10;
        float bv = ap[0]; int bi = 0;
        for (int i = 1; i < 10; ++i) { if (ap[i] > bv) { bv = ap[i]; bi = i; } }
        out[OFF_LA + b] = (float)bi;
    }
}

// ---------------- phase C: per-(b,rank) mask DCT + threshold + interms ----------------
__global__ __launch_bounds__(256) void mask_kernel(const float* __restrict__ vec,
                                                   const float* __restrict__ interms,
                                                   const int* __restrict__ wsQ,
                                                   const float* __restrict__ wsD,
                                                   const int* __restrict__ wsZZ,
                                                   float* __restrict__ out) {
    int j = blockIdx.x;      // rank 0..49
    int b = blockIdx.y;      // batch
    int t = threadIdx.x;

    __shared__ float sD[23 * 128];
    __shared__ float sT[23 * 128];
    __shared__ float sB[23 * 24];
    __shared__ float redv[4];
    __shared__ int   redi[4];
    __shared__ float redmn[4], redmx[4];

    int q = wsQ[b * TOPK + j];

    for (int i = t; i < 23 * 128; i += 256) sD[i] = wsD[i];
    for (int i = t; i < 23 * 24; i += 256) sB[i] = 0.0f;
    __syncthreads();

    // scatter the 256 kept coefficients into the zigzag positions (k+l <= 22)
    {
        int kl = wsZZ[t];
        float x = vec[((size_t)(b * QQ + q)) * NKEEP + t];
        sB[(kl >> 5) * 24 + (kl & 31)] = x;
    }

    // interms argmax/max over 91 classes (sigmoid is monotone)
    int lane = t & 63, w = t >> 6;
    {
        float x = (t < CC) ? interms[((size_t)(b * QQ + q)) * CC + t] : -INFINITY;
        int xi = (t < CC) ? t : 0x7fffffff;
#pragma unroll
        for (int off = 32; off >= 1; off >>= 1) {
            float ov = __shfl_down(x, off);
            int   oi = __shfl_down(xi, off);
            bool better = (ov > x) || (ov == x && oi < xi);
            x = better ? ov : x;
            xi = better ? oi : xi;
        }
        if (lane == 0) { redv[w] = x; redi[w] = xi; }
    }
    __syncthreads();   // guards sB scatter + redv/redi

    if (t == 0) {
        float gv = redv[0]; int gi = redi[0];
        for (int k = 1; k < 4; ++k) {
            bool better = (redv[k] > gv) || (redv[k] == gv && redi[k] < gi);
            gv = better ? redv[k] : gv;
            gi = better ? redi[k] : gi;
        }
        out[OFF_SI + (size_t)b * TOPK + j] = 1.0f / (1.0f + expf(-gv));
        out[OFF_LI + (size_t)b * TOPK + j] = (float)gi;
    }

    // stage 1: T[l][n] = sum_k D[k][n] * B[k][l]   (k,l in 0..22)
    {
        int n = t & 127, h = t >> 7;
        float Dn[23];
#pragma unroll
        for (int k = 0; k < 23; ++k) Dn[k] = sD[k * 128 + n];
        for (int l = h; l < 23; l += 2) {
            float acc = 0.0f;
#pragma unroll
            for (int k = 0; k < 23; ++k) acc += Dn[k] * sB[k * 24 + l];
            sT[l * 128 + n] = acc;
        }
    }
    __syncthreads();

    // stage 2: out[n][m] = sum_l T[l][n] * D[l][m]  -- 8x8 register tile per thread
    int tr = t >> 4, tc = t & 15;
    float acc[8][8];
#pragma unroll
    for (int a = 0; a < 8; ++a)
#pragma unroll
        for (int c = 0; c < 8; ++c) acc[a][c] = 0.0f;

#pragma unroll
    for (int l = 0; l < 23; ++l) {
        const float4 Ta = *(const float4*)&sT[l * 128 + tr * 8];
        const float4 Tb = *(const float4*)&sT[l * 128 + tr * 8 + 4];
        const float4 Da = *(const float4*)&sD[l * 128 + tc * 8];
        const float4 Db = *(const float4*)&sD[l * 128 + tc * 8 + 4];
        float Tv[8] = {Ta.x, Ta.y, Ta.z, Ta.w, Tb.x, Tb.y, Tb.z, Tb.w};
        float Dv[8] = {Da.x, Da.y, Da.z, Da.w, Db.x, Db.y, Db.z, Db.w};
#pragma unroll
        for (int a = 0; a < 8; ++a)
#pragma unroll
            for (int c = 0; c < 8; ++c) acc[a][c] += Tv[a] * Dv[c];
    }

    // block min/max
    float mn = acc[0][0], mx = acc[0][0];
#pragma unroll
    for (int a = 0; a < 8; ++a)
#pragma unroll
        for (int c = 0; c < 8; ++c) {
            mn = fminf(mn, acc[a][c]);
            mx = fmaxf(mx, acc[a][c]);
        }
#pragma unroll
    for (int off = 32; off >= 1; off >>= 1) {
        mn = fminf(mn, __shfl_down(mn, off));
        mx = fmaxf(mx, __shfl_down(mx, off));
    }
    if (lane == 0) { redmn[w] = mn; redmx[w] = mx; }
    __syncthreads();
    float gmn = fminf(fminf(redmn[0], redmn[1]), fminf(redmn[2], redmn[3]));
    float gmx = fmaxf(fmaxf(redmx[0], redmx[1]), fmaxf(redmx[2], redmx[3]));
    float thr = 0.5f * (gmx + gmn);

    size_t base = OFF_MASKS + ((size_t)(b * TOPK + j)) * 16384 + (size_t)tc * 8;
#pragma unroll
    for (int a = 0; a < 8; ++a) {
        int n = tr * 8 + a;
        float4 w0 = make_float4(acc[a][0] > thr ? 1.0f : 0.0f,
                                acc[a][1] > thr ? 1.0f : 0.0f,
                                acc[a][2] > thr ? 1.0f : 0.0f,
                                acc[a][3] > thr ? 1.0f : 0.0f);
        float4 w1 = make_float4(acc[a][4] > thr ? 1.0f : 0.0f,
                                acc[a][5] > thr ? 1.0f : 0.0f,
                                acc[a][6] > thr ? 1.0f : 0.0f,
                                acc[a][7] > thr ? 1.0f : 0.0f);
        *(float4*)&out[base + (size_t)n * 128]     = w0;
        *(float4*)&out[base + (size_t)n * 128 + 4] = w1;
    }
}

extern "C" void kernel_launch(void* const* d_in, const int* in_sizes, int n_in,
                              void* d_out, int out_size, void* d_ws, size_t ws_size,
                              hipStream_t stream) {
    const float* logits  = (const float*)d_in[0];
    const float* bbox    = (const float*)d_in[1];
    const float* vec     = (const float*)d_in[2];
    const float* interms = (const float*)d_in[3];
    const float* actions = (const float*)d_in[4];
    const int*   tsz     = (const int*)d_in[5];
    float* out = (float*)d_out;

    // workspace carve-out (~122 KB)
    float* wsD  = (float*)d_ws;            // 23*128 = 2944 floats
    int*   wsZZ = (int*)(wsD + 2944);      // 256 ints
    float* wsCV = (float*)(wsZZ + 256);    // 32*8*50 = 12800 floats
    int*   wsCP = (int*)(wsCV + 12800);    // 12800 ints
    int*   wsQ  = wsCP + 12800;            // 1600 ints

    hipLaunchKernelGGL(init_tables, dim3(12), dim3(256), 0, stream, wsD, wsZZ);
    hipLaunchKernelGGL(topk_partial, dim3(BB * NCH), dim3(256), 0, stream, logits, wsCV, wsCP);
    hipLaunchKernelGGL(topk_merge, dim3(BB), dim3(64), 0, stream, wsCV, wsCP, bbox, actions, tsz, out, wsQ);
    hipLaunchKernelGGL(mask_kernel, dim3(TOPK, BB), dim3(256), 0, stream, vec, interms, wsQ, wsD, wsZZ, out);
}

// Round 2
// 174.366 us; speedup vs baseline: 1.4898x; 1.4898x over previous
//
#include <hip/hip_runtime.h>
#include <math.h>

#define BB 32
#define QQ 300
#define CC 91
#define TOPK 50
#define NKEEP 256
#define ML 128
#define QC (QQ * CC)        // 27300
#define NPT 27              // ceil(27300/1024)
#define EQCAP 256

// output layout (flat float32, reference return order)
#define OFF_SCORES ((size_t)0)
#define OFF_LABELS ((size_t)1600)
#define OFF_BOXES  ((size_t)3200)
#define OFF_MASKS  ((size_t)9600)
#define OFF_SI     ((size_t)26224000)
#define OFF_LI     ((size_t)26225600)
#define OFF_LA     ((size_t)26227200)

// ---------------- init: DCT rows 0..22 (fp64 -> fp32) + zigzag table (parallel) ----------------
__global__ void init_tables(float* __restrict__ wsD, int* __restrict__ wsZZ) {
    int idx = blockIdx.x * 256 + threadIdx.x;
    if (idx < 23 * 128) {
        int k = idx >> 7, m = idx & 127;
        double v = cos((M_PI * (2.0 * (double)m + 1.0) * (double)k) / 256.0) * 0.125;
        if (k == 0) v *= sqrt(0.5);
        wsD[idx] = (float)v;
    }
    if (blockIdx.x == 0 && threadIdx.x < NKEEP) {
        int j = threadIdx.x;
        // diagonal s: tri(s) <= j < tri(s+1); j<256 => s<=22 (<127, no clipping)
        int s = 0;
        while ((s + 1) * (s + 2) / 2 <= j) ++s;
        int o = j - s * (s + 1) / 2;
        int r = (s & 1) ? o : (s - o);
        int c = s - r;
        wsZZ[j] = (r << 5) | c;
    }
}

// ---------------- fused top-k: exact radix select, one block per batch ----------------
__global__ __launch_bounds__(1024) void topk_kernel(const float* __restrict__ logits,
                                                    const float* __restrict__ bbox,
                                                    const float* __restrict__ actions,
                                                    const int* __restrict__ tsz,
                                                    float* __restrict__ out,
                                                    int* __restrict__ wsQ) {
    int b = blockIdx.x;
    int t = threadIdx.x;

    __shared__ uint32_t hist[256];
    __shared__ uint32_t scn[256];
    __shared__ uint32_t sPrefix;
    __shared__ int      sKth;
    __shared__ uint32_t cKey[TOPK];
    __shared__ int      cIdx[TOPK];
    __shared__ int      cntGt, cntEq;
    __shared__ int      eqBuf[EQCAP];
    __shared__ int      sMin;

    // load keys into registers (monotone float->uint transform; larger float => larger key)
    uint32_t key[NPT];
    const float* base = logits + (size_t)b * QC;
#pragma unroll
    for (int i = 0; i < NPT; ++i) {
        int p = t + 1024 * i;
        uint32_t k = 0u;  // sentinel below every finite key
        if (p < QC) {
            uint32_t u = __float_as_uint(base[p]);
            k = (u >> 31) ? ~u : (u | 0x80000000u);
        }
        key[i] = k;
    }

    if (t == 0) { cntGt = 0; cntEq = 0; }

    // MSB-first radix select: find key T of the 50th-largest element
    uint32_t prefix = 0;
    int kth = TOPK;
    for (int pass = 0; pass < 4; ++pass) {
        int shift = 24 - 8 * pass;
        if (t < 256) hist[t] = 0;
        __syncthreads();
        uint32_t pmask = (pass == 0) ? 0u : (0xFFFFFFFFu << (shift + 8));
#pragma unroll
        for (int i = 0; i < NPT; ++i) {
            uint32_t k = key[i];
            if ((k & pmask) == prefix) atomicAdd(&hist[(k >> shift) & 255u], 1u);
        }
        __syncthreads();
        // suffix-inclusive scan: scn[i] = count of matching keys with byte >= i
        if (t < 256) scn[t] = hist[t];
        __syncthreads();
        for (int st = 1; st < 256; st <<= 1) {
            uint32_t v = 0;
            if (t < 256 && t + st < 256) v = scn[t + st];
            __syncthreads();
            if (t < 256) scn[t] += v;
            __syncthreads();
        }
        if (t < 256) {
            int cge = (int)scn[t];
            int cgt = (t < 255) ? (int)scn[t + 1] : 0;
            if (cge >= kth && cgt < kth) {   // exactly one bin satisfies this
                sPrefix = prefix | ((uint32_t)t << shift);
                sKth = kth - cgt;
            }
        }
        __syncthreads();
        prefix = sPrefix;
        kth = sKth;
        __syncthreads();
    }

    uint32_t T = prefix;        // exact key of the 50th largest element
    int need = kth;             // how many ==T elements to take (smallest indices)
    int cgt = TOPK - need;      // count of strictly-greater elements

    // compact: strictly-greater go straight to candidate slots; equals to eq buffer
#pragma unroll
    for (int i = 0; i < NPT; ++i) {
        uint32_t k = key[i];
        int p = t + 1024 * i;
        if (k > T) {
            int pos = atomicAdd(&cntGt, 1);
            cKey[pos] = k; cIdx[pos] = p;
        } else if (k == T) {
            int pos = atomicAdd(&cntEq, 1);
            if (pos < EQCAP) eqBuf[pos] = p;
        }
    }
    __syncthreads();

    if (cntEq <= EQCAP) {
        // rank eq indices ascending; take the `need` smallest
        for (int j = t; j < cntEq; j += 1024) {
            int my = eqBuf[j];
            int rank = 0;
            for (int m = 0; m < cntEq; ++m) rank += (eqBuf[m] < my);
            if (rank < need) { cKey[cgt + rank] = T; cIdx[cgt + rank] = my; }
        }
        __syncthreads();
    } else {
        // overflow fallback: iterative block-wide min-index scan (ties beyond EQCAP)
        for (int r = 0; r < need; ++r) {
            if (t == 0) sMin = 0x7fffffff;
            __syncthreads();
            int loc = 0x7fffffff;
#pragma unroll
            for (int i = 0; i < NPT; ++i)
                if (key[i] == T) { int p = t + 1024 * i; loc = min(loc, p); }
            atomicMin(&sMin, loc);
            __syncthreads();
            int m = sMin;
#pragma unroll
            for (int i = 0; i < NPT; ++i)
                if (t + 1024 * i == m) key[i] = 0;
            if (t == 0) { cKey[cgt + r] = T; cIdx[cgt + r] = m; }
            __syncthreads();
        }
    }

    // rank the 50 candidates (key desc, index asc) and emit outputs
    if (t < TOPK) {
        uint32_t myk = cKey[t]; int myi = cIdx[t];
        int rank = 0;
        for (int m = 0; m < TOPK; ++m) {
            uint32_t ok = cKey[m]; int oi = cIdx[m];
            rank += (ok > myk) || (ok == myk && oi < myi);
        }
        uint32_t u = (myk >> 31) ? (myk & 0x7fffffffu) : ~myk;  // invert transform
        float val = __uint_as_float(u);
        int q = myi / CC;
        int label = myi - q * CC;
        out[OFF_SCORES + b * TOPK + rank] = 1.0f / (1.0f + expf(-val));
        out[OFF_LABELS + b * TOPK + rank] = (float)label;
        wsQ[b * TOPK + rank] = q;
        const float* bbp = bbox + ((size_t)(b * QQ + q)) * 4;
        float cx = bbp[0], cy = bbp[1], bw = bbp[2], bh = bbp[3];
        float ih = (float)tsz[b * 2 + 0];
        float iw = (float)tsz[b * 2 + 1];
        float* bo = out + OFF_BOXES + ((size_t)(b * TOPK + rank)) * 4;
        bo[0] = (cx - 0.5f * bw) * iw;
        bo[1] = (cy - 0.5f * bh) * ih;
        bo[2] = (cx + 0.5f * bw) * iw;
        bo[3] = (cy + 0.5f * bh) * ih;
    }
    if (t == 0) {
        const float* ap = actions + (size_t)b * 10;
        float bv = ap[0]; int bi = 0;
        for (int i = 1; i < 10; ++i) { if (ap[i] > bv) { bv = ap[i]; bi = i; } }
        out[OFF_LA + b] = (float)bi;
    }
}

// ---------------- per-(b,rank) mask DCT + threshold + interms ----------------
__global__ __launch_bounds__(256) void mask_kernel(const float* __restrict__ vec,
                                                   const float* __restrict__ interms,
                                                   const int* __restrict__ wsQ,
                                                   const float* __restrict__ wsD,
                                                   const int* __restrict__ wsZZ,
                                                   float* __restrict__ out) {
    int j = blockIdx.x;      // rank 0..49
    int b = blockIdx.y;      // batch
    int t = threadIdx.x;

    __shared__ float sD[23 * 128];
    __shared__ float sT[23 * 128];
    __shared__ float sB[23 * 24];
    __shared__ float redv[4];
    __shared__ int   redi[4];
    __shared__ float redmn[4], redmx[4];

    int q = wsQ[b * TOPK + j];

    for (int i = t; i < 23 * 128; i += 256) sD[i] = wsD[i];
    for (int i = t; i < 23 * 24; i += 256) sB[i] = 0.0f;
    __syncthreads();

    // scatter the 256 kept coefficients into the zigzag positions (k+l <= 22)
    {
        int kl = wsZZ[t];
        float x = vec[((size_t)(b * QQ + q)) * NKEEP + t];
        sB[(kl >> 5) * 24 + (kl & 31)] = x;
    }

    // interms argmax/max over 91 classes (sigmoid is monotone)
    int lane = t & 63, w = t >> 6;
    {
        float x = (t < CC) ? interms[((size_t)(b * QQ + q)) * CC + t] : -INFINITY;
        int xi = (t < CC) ? t : 0x7fffffff;
#pragma unroll
        for (int off = 32; off >= 1; off >>= 1) {
            float ov = __shfl_down(x, off);
            int   oi = __shfl_down(xi, off);
            bool better = (ov > x) || (ov == x && oi < xi);
            x = better ? ov : x;
            xi = better ? oi : xi;
        }
        if (lane == 0) { redv[w] = x; redi[w] = xi; }
    }
    __syncthreads();   // guards sB scatter + redv/redi

    if (t == 0) {
        float gv = redv[0]; int gi = redi[0];
        for (int k = 1; k < 4; ++k) {
            bool better = (redv[k] > gv) || (redv[k] == gv && redi[k] < gi);
            gv = better ? redv[k] : gv;
            gi = better ? redi[k] : gi;
        }
        out[OFF_SI + (size_t)b * TOPK + j] = 1.0f / (1.0f + expf(-gv));
        out[OFF_LI + (size_t)b * TOPK + j] = (float)gi;
    }

    // stage 1: T[l][n] = sum_k D[k][n] * B[k][l]   (k,l in 0..22)
    {
        int n = t & 127, h = t >> 7;
        float Dn[23];
#pragma unroll
        for (int k = 0; k < 23; ++k) Dn[k] = sD[k * 128 + n];
        for (int l = h; l < 23; l += 2) {
            float acc = 0.0f;
#pragma unroll
            for (int k = 0; k < 23; ++k) acc += Dn[k] * sB[k * 24 + l];
            sT[l * 128 + n] = acc;
        }
    }
    __syncthreads();

    // stage 2: out[n][m] = sum_l T[l][n] * D[l][m]  -- 8x8 register tile per thread
    int tr = t >> 4, tc = t & 15;
    float acc[8][8];
#pragma unroll
    for (int a = 0; a < 8; ++a)
#pragma unroll
        for (int c = 0; c < 8; ++c) acc[a][c] = 0.0f;

#pragma unroll
    for (int l = 0; l < 23; ++l) {
        const float4 Ta = *(const float4*)&sT[l * 128 + tr * 8];
        const float4 Tb = *(const float4*)&sT[l * 128 + tr * 8 + 4];
        const float4 Da = *(const float4*)&sD[l * 128 + tc * 8];
        const float4 Db = *(const float4*)&sD[l * 128 + tc * 8 + 4];
        float Tv[8] = {Ta.x, Ta.y, Ta.z, Ta.w, Tb.x, Tb.y, Tb.z, Tb.w};
        float Dv[8] = {Da.x, Da.y, Da.z, Da.w, Db.x, Db.y, Db.z, Db.w};
#pragma unroll
        for (int a = 0; a < 8; ++a)
#pragma unroll
            for (int c = 0; c < 8; ++c) acc[a][c] += Tv[a] * Dv[c];
    }

    // block min/max
    float mn = acc[0][0], mx = acc[0][0];
#pragma unroll
    for (int a = 0; a < 8; ++a)
#pragma unroll
        for (int c = 0; c < 8; ++c) {
            mn = fminf(mn, acc[a][c]);
            mx = fmaxf(mx, acc[a][c]);
        }
#pragma unroll
    for (int off = 32; off >= 1; off >>= 1) {
        mn = fminf(mn, __shfl_down(mn, off));
        mx = fmaxf(mx, __shfl_down(mx, off));
    }
    if (lane == 0) { redmn[w] = mn; redmx[w] = mx; }
    __syncthreads();
    float gmn = fminf(fminf(redmn[0], redmn[1]), fminf(redmn[2], redmn[3]));
    float gmx = fmaxf(fmaxf(redmx[0], redmx[1]), fmaxf(redmx[2], redmx[3]));
    float thr = 0.5f * (gmx + gmn);

    size_t bse = OFF_MASKS + ((size_t)(b * TOPK + j)) * 16384 + (size_t)tc * 8;
#pragma unroll
    for (int a = 0; a < 8; ++a) {
        int n = tr * 8 + a;
        float4 w0 = make_float4(acc[a][0] > thr ? 1.0f : 0.0f,
                                acc[a][1] > thr ? 1.0f : 0.0f,
                                acc[a][2] > thr ? 1.0f : 0.0f,
                                acc[a][3] > thr ? 1.0f : 0.0f);
        float4 w1 = make_float4(acc[a][4] > thr ? 1.0f : 0.0f,
                                acc[a][5] > thr ? 1.0f : 0.0f,
                                acc[a][6] > thr ? 1.0f : 0.0f,
                                acc[a][7] > thr ? 1.0f : 0.0f);
        *(float4*)&out[bse + (size_t)n * 128]     = w0;
        *(float4*)&out[bse + (size_t)n * 128 + 4] = w1;
    }
}

extern "C" void kernel_launch(void* const* d_in, const int* in_sizes, int n_in,
                              void* d_out, int out_size, void* d_ws, size_t ws_size,
                              hipStream_t stream) {
    const float* logits  = (const float*)d_in[0];
    const float* bbox    = (const float*)d_in[1];
    const float* vec     = (const float*)d_in[2];
    const float* interms = (const float*)d_in[3];
    const float* actions = (const float*)d_in[4];
    const int*   tsz     = (const int*)d_in[5];
    float* out = (float*)d_out;

    float* wsD  = (float*)d_ws;            // 23*128 = 2944 floats
    int*   wsZZ = (int*)(wsD + 2944);      // 256 ints
    int*   wsQ  = wsZZ + 256;              // 1600 ints

    hipLaunchKernelGGL(init_tables, dim3(12), dim3(256), 0, stream, wsD, wsZZ);
    hipLaunchKernelGGL(topk_kernel, dim3(BB), dim3(1024), 0, stream,
                       logits, bbox, actions, tsz, out, wsQ);
    hipLaunchKernelGGL(mask_kernel, dim3(TOPK, BB), dim3(256), 0, stream,
                       vec, interms, wsQ, wsD, wsZZ, out);
}

// Round 3
// 173.156 us; speedup vs baseline: 1.5002x; 1.0070x over previous
//
#include <hip/hip_runtime.h>
#include <math.h>

#define BB 32
#define QQ 300
#define CC 91
#define TOPK 50
#define NKEEP 256
#define ML 128
#define QC (QQ * CC)        // 27300
#define QC4 (QC / 4)        // 6825 float4s (exact)
#define NPT4 7              // ceil(6825/1024)
#define EQCAP 256
#define NWAVE 16

// output layout (flat float32, reference return order)
#define OFF_SCORES ((size_t)0)
#define OFF_LABELS ((size_t)1600)
#define OFF_BOXES  ((size_t)3200)
#define OFF_MASKS  ((size_t)9600)
#define OFF_SI     ((size_t)26224000)
#define OFF_LI     ((size_t)26225600)
#define OFF_LA     ((size_t)26227200)

__device__ __forceinline__ uint32_t fkey(float f) {
    uint32_t u = __float_as_uint(f);
    return (u >> 31) ? ~u : (u | 0x80000000u);
}

// ---------------- fused: table init (block 0) + exact radix top-k, one block/batch ----------------
__global__ __launch_bounds__(1024) void topk_kernel(const float* __restrict__ logits,
                                                    const float* __restrict__ bbox,
                                                    const float* __restrict__ actions,
                                                    const int* __restrict__ tsz,
                                                    float* __restrict__ out,
                                                    int* __restrict__ wsQ,
                                                    float* __restrict__ wsD,
                                                    int* __restrict__ wsZZ) {
    int b = blockIdx.x;
    int t = threadIdx.x;

    // ---- block 0: build DCT rows 0..22 (fp64, matches numpy) + zigzag table ----
    if (b == 0) {
        for (int idx = t; idx < 23 * 128; idx += 1024) {
            int k = idx >> 7, m = idx & 127;
            double v = cos((M_PI * (2.0 * (double)m + 1.0) * (double)k) / 256.0) * 0.125;
            if (k == 0) v *= sqrt(0.5);
            wsD[idx] = (float)v;
        }
        if (t < NKEEP) {
            int j = t;
            int s = 0;
            while ((s + 1) * (s + 2) / 2 <= j) ++s;
            int o = j - s * (s + 1) / 2;
            int r = (s & 1) ? o : (s - o);
            int c = s - r;
            wsZZ[j] = (r << 5) | c;
        }
    }

    __shared__ uint32_t hist[NWAVE * 256];   // per-wave privatized histograms
    __shared__ uint32_t scn[256];            // summed per-bin counts
    __shared__ uint32_t sPrefix;
    __shared__ int      sKth;
    __shared__ uint32_t cKey[TOPK];
    __shared__ int      cIdx[TOPK];
    __shared__ int      cntGt, cntEq;
    __shared__ int      eqBuf[EQCAP];
    __shared__ int      sMin;

    // ---- load keys (float4) ----
    const float4* base4 = (const float4*)(logits + (size_t)b * QC);
    uint32_t key[NPT4][4];
#pragma unroll
    for (int i = 0; i < NPT4; ++i) {
        int p4 = t + 1024 * i;
        if (p4 < QC4) {
            float4 v = base4[p4];
            key[i][0] = fkey(v.x); key[i][1] = fkey(v.y);
            key[i][2] = fkey(v.z); key[i][3] = fkey(v.w);
        } else {
            key[i][0] = key[i][1] = key[i][2] = key[i][3] = 0u;  // below all real keys
        }
    }

    if (t == 0) { cntGt = 0; cntEq = 0; }

    int lane = t & 63, w = t >> 6;
    uint32_t* myh = &hist[w * 256];

    // ---- MSB-first radix select: find key T of the 50th-largest ----
    uint32_t prefix = 0;
    int kth = TOPK;
    for (int pass = 0; pass < 4; ++pass) {
        int shift = 24 - 8 * pass;
        for (int i = t; i < NWAVE * 256; i += 1024) hist[i] = 0;
        __syncthreads();
        uint32_t pmask = (pass == 0) ? 0u : (0xFFFFFFFFu << (shift + 8));
#pragma unroll
        for (int i = 0; i < NPT4; ++i) {
#pragma unroll
            for (int c = 0; c < 4; ++c) {
                uint32_t k = key[i][c];
                if ((k & pmask) == prefix) atomicAdd(&myh[(k >> shift) & 255u], 1u);
            }
        }
        __syncthreads();
        // sum 16 wave-hists -> scn[bin] (threads 0..255, conflict-free)
        if (t < 256) {
            uint32_t s = 0;
#pragma unroll
            for (int ww = 0; ww < NWAVE; ++ww) s += hist[ww * 256 + t];
            scn[t] = s;
        }
        __syncthreads();
        // wave 0: register suffix-scan over 256 bins, pick boundary bin
        if (t < 64) {
            uint4 h4 = *(const uint4*)&scn[lane * 4];
            uint32_t s3 = h4.w;
            uint32_t s2 = h4.z + s3;
            uint32_t s1 = h4.y + s2;
            uint32_t s0 = h4.x + s1;
            uint32_t inc = s0;
#pragma unroll
            for (int off = 1; off < 64; off <<= 1) {
                uint32_t v = __shfl_down(inc, off);
                if (lane + off < 64) inc += v;
            }
            uint32_t higher = inc - s0;   // strictly-higher lanes' total
            uint32_t sarr[4] = {s0, s1, s2, s3};
            uint32_t harr[4] = {h4.x, h4.y, h4.z, h4.w};
#pragma unroll
            for (int c = 0; c < 4; ++c) {
                int cge = (int)(sarr[c] + higher);
                int cgt = cge - (int)harr[c];
                if (cge >= kth && cgt < kth) {
                    sPrefix = prefix | ((uint32_t)(lane * 4 + c) << shift);
                    sKth = kth - cgt;
                }
            }
        }
        __syncthreads();
        prefix = sPrefix;
        kth = sKth;
    }

    uint32_t T = prefix;        // exact key of the 50th largest
    int need = kth;             // how many ==T to take (smallest indices)
    int cgt = TOPK - need;

    // ---- compaction ----
#pragma unroll
    for (int i = 0; i < NPT4; ++i) {
#pragma unroll
        for (int c = 0; c < 4; ++c) {
            uint32_t k = key[i][c];
            if (k > T) {
                int pos = atomicAdd(&cntGt, 1);
                cKey[pos] = k; cIdx[pos] = 4 * (t + 1024 * i) + c;
            } else if (k == T) {
                int pos = atomicAdd(&cntEq, 1);
                if (pos < EQCAP) eqBuf[pos] = 4 * (t + 1024 * i) + c;
            }
        }
    }
    __syncthreads();

    if (cntEq <= EQCAP) {
        for (int j = t; j < cntEq; j += 1024) {
            int my = eqBuf[j];
            int rank = 0;
            for (int m = 0; m < cntEq; ++m) rank += (eqBuf[m] < my);
            if (rank < need) { cKey[cgt + rank] = T; cIdx[cgt + rank] = my; }
        }
        __syncthreads();
    } else {
        for (int r = 0; r < need; ++r) {
            if (t == 0) sMin = 0x7fffffff;
            __syncthreads();
            int loc = 0x7fffffff;
#pragma unroll
            for (int i = 0; i < NPT4; ++i)
#pragma unroll
                for (int c = 0; c < 4; ++c)
                    if (key[i][c] == T) loc = min(loc, 4 * (t + 1024 * i) + c);
            atomicMin(&sMin, loc);
            __syncthreads();
            int m = sMin;
#pragma unroll
            for (int i = 0; i < NPT4; ++i)
#pragma unroll
                for (int c = 0; c < 4; ++c)
                    if (4 * (t + 1024 * i) + c == m) key[i][c] = 0;
            if (t == 0) { cKey[cgt + r] = T; cIdx[cgt + r] = m; }
            __syncthreads();
        }
    }

    // ---- rank 50 candidates (key desc, index asc) and emit ----
    if (t < TOPK) {
        uint32_t myk = cKey[t]; int myi = cIdx[t];
        int rank = 0;
        for (int m = 0; m < TOPK; ++m) {
            uint32_t ok = cKey[m]; int oi = cIdx[m];
            rank += (ok > myk) || (ok == myk && oi < myi);
        }
        uint32_t u = (myk >> 31) ? (myk & 0x7fffffffu) : ~myk;
        float val = __uint_as_float(u);
        int q = myi / CC;
        int label = myi - q * CC;
        out[OFF_SCORES + b * TOPK + rank] = 1.0f / (1.0f + expf(-val));
        out[OFF_LABELS + b * TOPK + rank] = (float)label;
        wsQ[b * TOPK + rank] = q;
        const float* bbp = bbox + ((size_t)(b * QQ + q)) * 4;
        float cx = bbp[0], cy = bbp[1], bw = bbp[2], bh = bbp[3];
        float ih = (float)tsz[b * 2 + 0];
        float iw = (float)tsz[b * 2 + 1];
        float* bo = out + OFF_BOXES + ((size_t)(b * TOPK + rank)) * 4;
        bo[0] = (cx - 0.5f * bw) * iw;
        bo[1] = (cy - 0.5f * bh) * ih;
        bo[2] = (cx + 0.5f * bw) * iw;
        bo[3] = (cy + 0.5f * bh) * ih;
    }
    if (t == 0) {
        const float* ap = actions + (size_t)b * 10;
        float bv = ap[0]; int bi = 0;
        for (int i = 1; i < 10; ++i) { if (ap[i] > bv) { bv = ap[i]; bi = i; } }
        out[OFF_LA + b] = (float)bi;
    }
}

// ---------------- per-(b,rank) mask DCT + threshold + interms ----------------
__global__ __launch_bounds__(256) void mask_kernel(const float* __restrict__ vec,
                                                   const float* __restrict__ interms,
                                                   const int* __restrict__ wsQ,
                                                   const float* __restrict__ wsD,
                                                   const int* __restrict__ wsZZ,
                                                   float* __restrict__ out) {
    int j = blockIdx.x;      // rank 0..49
    int b = blockIdx.y;      // batch
    int t = threadIdx.x;

    __shared__ float sD[23 * 128];
    __shared__ float sT[23 * 128];
    __shared__ float sB[23 * 24];
    __shared__ float redv[4];
    __shared__ int   redi[4];
    __shared__ float redmn[4], redmx[4];

    int q = wsQ[b * TOPK + j];

    for (int i = t; i < 23 * 128; i += 256) sD[i] = wsD[i];
    for (int i = t; i < 23 * 24; i += 256) sB[i] = 0.0f;
    __syncthreads();

    // scatter the 256 kept coefficients into zigzag positions (k+l <= 22)
    {
        int kl = wsZZ[t];
        float x = vec[((size_t)(b * QQ + q)) * NKEEP + t];
        sB[(kl >> 5) * 24 + (kl & 31)] = x;
    }

    // interms argmax/max over 91 classes (sigmoid is monotone)
    int lane = t & 63, w = t >> 6;
    {
        float x = (t < CC) ? interms[((size_t)(b * QQ + q)) * CC + t] : -INFINITY;
        int xi = (t < CC) ? t : 0x7fffffff;
#pragma unroll
        for (int off = 32; off >= 1; off >>= 1) {
            float ov = __shfl_down(x, off);
            int   oi = __shfl_down(xi, off);
            bool better = (ov > x) || (ov == x && oi < xi);
            x = better ? ov : x;
            xi = better ? oi : xi;
        }
        if (lane == 0) { redv[w] = x; redi[w] = xi; }
    }
    __syncthreads();   // guards sB scatter + redv/redi

    if (t == 0) {
        float gv = redv[0]; int gi = redi[0];
        for (int k = 1; k < 4; ++k) {
            bool better = (redv[k] > gv) || (redv[k] == gv && redi[k] < gi);
            gv = better ? redv[k] : gv;
            gi = better ? redi[k] : gi;
        }
        out[OFF_SI + (size_t)b * TOPK + j] = 1.0f / (1.0f + expf(-gv));
        out[OFF_LI + (size_t)b * TOPK + j] = (float)gi;
    }

    // stage 1: T[l][n] = sum_k D[k][n] * B[k][l]   (k,l in 0..22)
    {
        int n = t & 127, h = t >> 7;
        float Dn[23];
#pragma unroll
        for (int k = 0; k < 23; ++k) Dn[k] = sD[k * 128 + n];
        for (int l = h; l < 23; l += 2) {
            float acc = 0.0f;
#pragma unroll
            for (int k = 0; k < 23; ++k) acc += Dn[k] * sB[k * 24 + l];
            sT[l * 128 + n] = acc;
        }
    }
    __syncthreads();

    // stage 2: out[n][m] = sum_l T[l][n] * D[l][m]  -- 8x8 register tile per thread
    int tr = t >> 4, tc = t & 15;
    float acc[8][8];
#pragma unroll
    for (int a = 0; a < 8; ++a)
#pragma unroll
        for (int c = 0; c < 8; ++c) acc[a][c] = 0.0f;

#pragma unroll
    for (int l = 0; l < 23; ++l) {
        const float4 Ta = *(const float4*)&sT[l * 128 + tr * 8];
        const float4 Tb = *(const float4*)&sT[l * 128 + tr * 8 + 4];
        const float4 Da = *(const float4*)&sD[l * 128 + tc * 8];
        const float4 Db = *(const float4*)&sD[l * 128 + tc * 8 + 4];
        float Tv[8] = {Ta.x, Ta.y, Ta.z, Ta.w, Tb.x, Tb.y, Tb.z, Tb.w};
        float Dv[8] = {Da.x, Da.y, Da.z, Da.w, Db.x, Db.y, Db.z, Db.w};
#pragma unroll
        for (int a = 0; a < 8; ++a)
#pragma unroll
            for (int c = 0; c < 8; ++c) acc[a][c] += Tv[a] * Dv[c];
    }

    // block min/max
    float mn = acc[0][0], mx = acc[0][0];
#pragma unroll
    for (int a = 0; a < 8; ++a)
#pragma unroll
        for (int c = 0; c < 8; ++c) {
            mn = fminf(mn, acc[a][c]);
            mx = fmaxf(mx, acc[a][c]);
        }
#pragma unroll
    for (int off = 32; off >= 1; off >>= 1) {
        mn = fminf(mn, __shfl_down(mn, off));
        mx = fmaxf(mx, __shfl_down(mx, off));
    }
    if (lane == 0) { redmn[w] = mn; redmx[w] = mx; }
    __syncthreads();
    float gmn = fminf(fminf(redmn[0], redmn[1]), fminf(redmn[2], redmn[3]));
    float gmx = fmaxf(fmaxf(redmx[0], redmx[1]), fmaxf(redmx[2], redmx[3]));
    float thr = 0.5f * (gmx + gmn);

    size_t bse = OFF_MASKS + ((size_t)(b * TOPK + j)) * 16384 + (size_t)tc * 8;
#pragma unroll
    for (int a = 0; a < 8; ++a) {
        int n = tr * 8 + a;
        float4 w0 = make_float4(acc[a][0] > thr ? 1.0f : 0.0f,
                                acc[a][1] > thr ? 1.0f : 0.0f,
                                acc[a][2] > thr ? 1.0f : 0.0f,
                                acc[a][3] > thr ? 1.0f : 0.0f);
        float4 w1 = make_float4(acc[a][4] > thr ? 1.0f : 0.0f,
                                acc[a][5] > thr ? 1.0f : 0.0f,
                                acc[a][6] > thr ? 1.0f : 0.0f,
                                acc[a][7] > thr ? 1.0f : 0.0f);
        *(float4*)&out[bse + (size_t)n * 128]     = w0;
        *(float4*)&out[bse + (size_t)n * 128 + 4] = w1;
    }
}

extern "C" void kernel_launch(void* const* d_in, const int* in_sizes, int n_in,
                              void* d_out, int out_size, void* d_ws, size_t ws_size,
                              hipStream_t stream) {
    const float* logits  = (const float*)d_in[0];
    const float* bbox    = (const float*)d_in[1];
    const float* vec     = (const float*)d_in[2];
    const float* interms = (const float*)d_in[3];
    const float* actions = (const float*)d_in[4];
    const int*   tsz     = (const int*)d_in[5];
    float* out = (float*)d_out;

    float* wsD  = (float*)d_ws;            // 23*128 = 2944 floats
    int*   wsZZ = (int*)(wsD + 2944);      // 256 ints
    int*   wsQ  = wsZZ + 256;              // 1600 ints

    hipLaunchKernelGGL(topk_kernel, dim3(BB), dim3(1024), 0, stream,
                       logits, bbox, actions, tsz, out, wsQ, wsD, wsZZ);
    hipLaunchKernelGGL(mask_kernel, dim3(TOPK, BB), dim3(256), 0, stream,
                       vec, interms, wsQ, wsD, wsZZ, out);
}